// Round 1
// baseline (159.198 us; speedup 1.0000x reference)
//
#include <hip/hip_runtime.h>
#include <float.h>

#define TPB   256   // threads per block
#define UPT   4     // A-points per thread (independent min chains for ILP)
#define CHUNK 512   // B-points per block pass (M-split for occupancy)

// One kernel covers BOTH directions (pred->gt and gt->pred) so a single
// launch fills the machine: grid = dir0_blocks + dir1_blocks.
// Partial mins are merged with integer atomicMin on float bits (d2 >= 0,
// so IEEE order == unsigned integer order). Exact & order-independent.
__global__ __launch_bounds__(TPB) void chamfer_min_kernel(
    const float* __restrict__ P, const float* __restrict__ G,
    unsigned int* __restrict__ minP, unsigned int* __restrict__ minG,
    int BS, int N, int M)
{
    const int nChunks0 = N / (TPB * UPT);
    const int mChunks0 = M / CHUNK;
    const int blocksDir0 = BS * nChunks0 * mChunks0;

    int bid = blockIdx.x;
    const float* A; const float* Bpts; unsigned int* outMin; int An, Bn;
    if (bid < blocksDir0) { A = P; Bpts = G; outMin = minP; An = N; Bn = M; }
    else { bid -= blocksDir0; A = G; Bpts = P; outMin = minG; An = M; Bn = N; }

    const int mChunks = Bn / CHUNK;
    const int nChunks = An / (TPB * UPT);
    const int mc = bid % mChunks;
    const int nc = (bid / mChunks) % nChunks;
    const int b  = bid / (mChunks * nChunks);

    const float* Ab = A + (size_t)b * An * 3;
    const float* Bb = Bpts + (size_t)b * Bn * 3;

    // Load this thread's UPT A-points into registers.
    float ax[UPT], ay[UPT], az[UPT], mn[UPT];
    const int nBase = nc * (TPB * UPT);
#pragma unroll
    for (int u = 0; u < UPT; ++u) {
        const int n = nBase + u * TPB + (int)threadIdx.x;
        ax[u] = Ab[3*n+0]; ay[u] = Ab[3*n+1]; az[u] = Ab[3*n+2];
        mn[u] = 3.0e38f;
    }

    // Walk CHUNK B-points. The B-point address is wave-uniform -> the
    // compiler emits scalar loads (s_load, L2-served); VALU ops read the
    // coords straight from SGPRs. 2x m-unroll x 4 A-points = 8 independent
    // min chains in flight.
    const int m0 = mc * CHUNK;
    for (int m = m0; m < m0 + CHUNK; m += 2) {
        const float bx0 = Bb[3*m+0], by0 = Bb[3*m+1], bz0 = Bb[3*m+2];
        const float bx1 = Bb[3*m+3], by1 = Bb[3*m+4], bz1 = Bb[3*m+5];
#pragma unroll
        for (int u = 0; u < UPT; ++u) {
            float dx0 = ax[u]-bx0, dy0 = ay[u]-by0, dz0 = az[u]-bz0;
            float d0  = dx0*dx0 + dy0*dy0 + dz0*dz0;   // fma chain
            float dx1 = ax[u]-bx1, dy1 = ay[u]-by1, dz1 = az[u]-bz1;
            float d1  = dx1*dx1 + dy1*dy1 + dz1*dz1;
            mn[u] = fminf(mn[u], d0);
            mn[u] = fminf(mn[u], d1);
        }
    }

#pragma unroll
    for (int u = 0; u < UPT; ++u) {
        const int n = nBase + u * TPB + (int)threadIdx.x;
        atomicMin(&outMin[(size_t)b * An + n], __float_as_uint(mn[u]));
    }
}

__global__ __launch_bounds__(256) void chamfer_reduce_kernel(
    const unsigned int* __restrict__ minP, const unsigned int* __restrict__ minG,
    float* __restrict__ out, int totalP, int totalG)
{
    __shared__ double sdata[256];
    double s1 = 0.0, s2 = 0.0;
    for (int i = (int)threadIdx.x; i < totalP; i += 256)
        s1 += (double)__uint_as_float(minP[i]);
    for (int i = (int)threadIdx.x; i < totalG; i += 256)
        s2 += (double)__uint_as_float(minG[i]);
    sdata[threadIdx.x] = s1 / (double)totalP + s2 / (double)totalG;
    __syncthreads();
    for (int off = 128; off > 0; off >>= 1) {
        if ((int)threadIdx.x < off) sdata[threadIdx.x] += sdata[threadIdx.x + off];
        __syncthreads();
    }
    if (threadIdx.x == 0) out[0] = (float)sdata[0];
}

extern "C" void kernel_launch(void* const* d_in, const int* in_sizes, int n_in,
                              void* d_out, int out_size, void* d_ws, size_t ws_size,
                              hipStream_t stream) {
    const float* pred = (const float*)d_in[0];
    const float* gt   = (const float*)d_in[1];
    float* out = (float*)d_out;

    const int BS = 4;            // batch
    const int N  = 8192;         // pred points per batch
    const int M  = 8192;         // gt points per batch
    (void)in_sizes; (void)n_in; (void)out_size; (void)ws_size;

    unsigned int* minP = (unsigned int*)d_ws;                  // B*N mins
    unsigned int* minG = minP + (size_t)BS * N;                // B*M mins

    // 0x7F7F7F7F as float = 3.39e38 -> larger than any real d2; integer
    // compare against real d2 bit patterns is always "greater". One memset
    // initializes both min arrays (graph-capture safe).
    hipMemsetAsync(d_ws, 0x7F, (size_t)(BS * N + BS * M) * sizeof(unsigned int), stream);

    const int blocksDir0 = BS * (N / (TPB * UPT)) * (M / CHUNK);
    const int blocksDir1 = BS * (M / (TPB * UPT)) * (N / CHUNK);
    chamfer_min_kernel<<<blocksDir0 + blocksDir1, TPB, 0, stream>>>(
        pred, gt, minP, minG, BS, N, M);

    chamfer_reduce_kernel<<<1, 256, 0, stream>>>(minP, minG, out, BS * N, BS * M);
}

// Round 2
// 58.771 us; speedup vs baseline: 2.7088x; 2.7088x over previous
//
#include <hip/hip_runtime.h>

typedef float f32x2 __attribute__((ext_vector_type(2)));
typedef float f32x8 __attribute__((ext_vector_type(8)));

#define TPB   256   // threads per block
#define UPT   4     // A-points per thread
#define CHUNK 256   // B-points per block pass

// ---- packed fp32 helpers (CDNA: V_PK_FMA_F32 on VGPR/SGPR pairs) ----
// D = A*B + C, two fp32 lanes at once. B comes straight from SGPR pair
// (uniform s_load data) — exactly 1 SGPR operand per instruction.
__device__ __forceinline__ f32x2 pk_fma_vsv(f32x2 a, f32x2 b_sgpr, f32x2 c) {
    f32x2 d;
    asm("v_pk_fma_f32 %0, %1, %2, %3" : "=v"(d) : "v"(a), "s"(b_sgpr), "v"(c));
    return d;
}
__device__ __forceinline__ float min3f(float a, float b, float c) {
    float d;
    asm("v_min3_f32 %0, %1, %2, %3" : "=v"(d) : "v"(a), "v"(b), "v"(c));
    return d;
}

// Build pair-transposed quads: PK[j] = (x0,x1, y0,y1, z0,z1, s0,s1) for
// points 2j,2j+1 where s = x^2+y^2+z^2. Also init the min arrays (replaces
// the memset). One array per point set; it serves as both the A-side
// (strided per-lane reads at setup) and B-side (s_load_dwordx8 pairs).
__global__ __launch_bounds__(256) void chamfer_prep_kernel(
    const float* __restrict__ P, const float* __restrict__ G,
    f32x8* __restrict__ PKP, f32x8* __restrict__ PKG,
    unsigned int* __restrict__ mins, int nPairs, int nMins)
{
    const int i = blockIdx.x * 256 + (int)threadIdx.x;
    if (i < nPairs) {
        {
            float x0=P[6*i],y0=P[6*i+1],z0=P[6*i+2],x1=P[6*i+3],y1=P[6*i+4],z1=P[6*i+5];
            PKP[i] = f32x8{x0,x1,y0,y1,z0,z1, x0*x0+y0*y0+z0*z0, x1*x1+y1*y1+z1*z1};
        }
        {
            float x0=G[6*i],y0=G[6*i+1],z0=G[6*i+2],x1=G[6*i+3],y1=G[6*i+4],z1=G[6*i+5];
            PKG[i] = f32x8{x0,x1,y0,y1,z0,z1, x0*x0+y0*y0+z0*z0, x1*x1+y1*y1+z1*z1};
        }
    }
    if (i < nMins) mins[i] = 0x7F7F7F7Fu;   // 3.39e38f > any real d2
}

// d2 = |a|^2 + (|b|^2 - 2 a.b). Track min of the parenthesized term; add
// |a|^2 once at the end. Inner loop per 2 B-points per A-point:
// 3 x v_pk_fma_f32 + 1 x v_min3_f32.
__global__ __launch_bounds__(TPB) void chamfer_min_kernel(
    const f32x8* __restrict__ PKP, const f32x8* __restrict__ PKG,
    unsigned int* __restrict__ minP, unsigned int* __restrict__ minG,
    int BS, int N, int M)
{
    const int blocksDir0 = BS * (N / (TPB * UPT)) * (M / CHUNK);

    int bid = blockIdx.x;
    const f32x8* Apk; const f32x8* Bpk; unsigned int* outMin; int An, Bn;
    if (bid < blocksDir0) { Apk = PKP; Bpk = PKG; outMin = minP; An = N; Bn = M; }
    else { bid -= blocksDir0; Apk = PKG; Bpk = PKP; outMin = minG; An = M; Bn = N; }

    const int mChunks = Bn / CHUNK;
    const int nChunks = An / (TPB * UPT);
    const int mc = bid % mChunks;
    const int nc = (bid / mChunks) % nChunks;
    const int b  = bid / (mChunks * nChunks);

    const float* Araw = (const float*)(Apk + (size_t)b * (An / 2));
    const f32x8* Bb   = Bpk + (size_t)b * (Bn / 2);

    // Per-thread A-points: -2*coords duplicated into packed pairs, |a|^2 kept.
    f32x2 a2x[UPT], a2y[UPT], a2z[UPT];
    float cc[UPT], mn[UPT];
    const int nBase = nc * (TPB * UPT);
#pragma unroll
    for (int u = 0; u < UPT; ++u) {
        const int n = nBase + u * TPB + (int)threadIdx.x;
        const int j = n >> 1, l = n & 1;
        const float x = Araw[8*j + 0 + l];
        const float y = Araw[8*j + 2 + l];
        const float z = Araw[8*j + 4 + l];
        cc[u]  = Araw[8*j + 6 + l];
        a2x[u] = f32x2{-2.f*x, -2.f*x};
        a2y[u] = f32x2{-2.f*y, -2.f*y};
        a2z[u] = f32x2{-2.f*z, -2.f*z};
        mn[u]  = 3.0e38f;
    }

    // Uniform s_load_dwordx8 per iteration: 4 SGPR pairs (xs,ys,zs,ss).
    const int jBase = (mc * CHUNK) >> 1;
#pragma unroll 2
    for (int jj = 0; jj < CHUNK / 2; ++jj) {
        const f32x8 q = Bb[jBase + jj];
        const f32x2 xs = {q[0], q[1]};
        const f32x2 ys = {q[2], q[3]};
        const f32x2 zs = {q[4], q[5]};
        const f32x2 ss = {q[6], q[7]};   // copied to a VGPR pair once, shared by all u
#pragma unroll
        for (int u = 0; u < UPT; ++u) {
            f32x2 t = pk_fma_vsv(a2x[u], xs, ss);
            t = pk_fma_vsv(a2y[u], ys, t);
            t = pk_fma_vsv(a2z[u], zs, t);
            mn[u] = min3f(mn[u], t[0], t[1]);
        }
    }

#pragma unroll
    for (int u = 0; u < UPT; ++u) {
        const int n = nBase + u * TPB + (int)threadIdx.x;
        const float v = fmaxf(cc[u] + mn[u], 0.0f);  // d2 >= 0 (guards rounding)
        atomicMin(&outMin[(size_t)b * An + n], __float_as_uint(v));
    }
}

__global__ __launch_bounds__(1024) void chamfer_reduce_kernel(
    const uint4* __restrict__ mins4, float* __restrict__ out, int q4P, int q4G)
{
    __shared__ double sdata[1024];
    const double wP = 1.0 / (4.0 * (double)q4P);
    const double wG = 1.0 / (4.0 * (double)q4G);
    double acc = 0.0;
    const int tot = q4P + q4G;
    for (int i = (int)threadIdx.x; i < tot; i += 1024) {
        const uint4 v = mins4[i];
        const double s = (double)__uint_as_float(v.x) + (double)__uint_as_float(v.y)
                       + (double)__uint_as_float(v.z) + (double)__uint_as_float(v.w);
        acc += (i < q4P) ? s * wP : s * wG;
    }
    sdata[threadIdx.x] = acc;
    __syncthreads();
    for (int off = 512; off > 0; off >>= 1) {
        if ((int)threadIdx.x < off) sdata[threadIdx.x] += sdata[threadIdx.x + off];
        __syncthreads();
    }
    if (threadIdx.x == 0) out[0] = (float)sdata[0];
}

extern "C" void kernel_launch(void* const* d_in, const int* in_sizes, int n_in,
                              void* d_out, int out_size, void* d_ws, size_t ws_size,
                              hipStream_t stream) {
    const float* pred = (const float*)d_in[0];
    const float* gt   = (const float*)d_in[1];
    float* out = (float*)d_out;
    (void)in_sizes; (void)n_in; (void)out_size; (void)ws_size;

    const int BS = 4, N = 8192, M = 8192;
    const int nMins  = BS * N + BS * M;        // 65536
    const int nPairs = BS * N / 2;             // 16384 pairs per set (N==M)

    // ws layout: [mins: 65536 u32][PKP: 16384 f32x8][PKG: 16384 f32x8] = 1.25 MB
    unsigned int* mins = (unsigned int*)d_ws;
    f32x8* PKP = (f32x8*)((char*)d_ws + (size_t)nMins * sizeof(unsigned int));
    f32x8* PKG = PKP + nPairs;
    unsigned int* minP = mins;
    unsigned int* minG = mins + (size_t)BS * N;

    chamfer_prep_kernel<<<(nMins + 255) / 256, 256, 0, stream>>>(
        pred, gt, PKP, PKG, mins, nPairs, nMins);

    const int blocksDir0 = BS * (N / (TPB * UPT)) * (M / CHUNK);
    const int blocksDir1 = BS * (M / (TPB * UPT)) * (N / CHUNK);
    chamfer_min_kernel<<<blocksDir0 + blocksDir1, TPB, 0, stream>>>(
        PKP, PKG, minP, minG, BS, N, M);

    chamfer_reduce_kernel<<<1, 1024, 0, stream>>>(
        (const uint4*)mins, out, BS * N / 4, BS * M / 4);
}